// Round 7
// baseline (214.420 us; speedup 1.0000x reference)
//
#include <hip/hip_runtime.h>
#include <math.h>

// Problem constants (match reference)
constexpr int B = 1024;
constexpr int S = 50;
constexpr int H = 64;
constexpr int V = 40000;
constexpr int N4 = B * V / 4;   // 10,240,000 float4 chunks in out[]

// ---------------------------------------------------------------------------
// Diagnostic + candidate-win fill: blit-style (one float4 per thread, no
// loop, 40000 blocks x 256 — mirrors fillBufferAligned's shape) but sweeps
// the buffer TWICE (second store at +N/2 mod N; distinct addresses -> no
// DCE; every line written twice -> ~328 MB writeback). Purpose: if the
// in-kernel store path is capped ~2 TB/s this dispatch runs ~165 us and
// becomes VISIBLE in the top-5 WITH its hbm counters; if stores run at
// fill-rate it costs ~50 us. Pre-committed outcome table in the journal.
// ---------------------------------------------------------------------------
typedef float floatx4 __attribute__((ext_vector_type(4)));

__global__ __launch_bounds__(256) void rrd_fill2x(floatx4* __restrict__ out4)
{
    const int t = blockIdx.x * 256 + threadIdx.x;          // t in [0, N4)
    const floatx4 z = {0.f, 0.f, 0.f, 0.f};
    out4[t] = z;                                           // sweep 1
    int u = t + N4 / 2; if (u >= N4) u -= N4;              // sweep 2, +N/2 mod N
    out4[u] = z;
}

// ---------------------------------------------------------------------------
// Compute kernel — UNCHANGED from R6 (core measured ~10-15 us via R5 probe):
// am + Ur staged into LDS (pad-65), l[k] one wave, scores wave-split,
// softmax + atomic scatter in wave 0 registers.
// ---------------------------------------------------------------------------
__global__ __launch_bounds__(256) void rrd_compute(
    const float* __restrict__ am,    // [B,S,H]
    const float* __restrict__ lm,    // [B,H]
    const int*   __restrict__ items, // [B,S] int32
    const float* __restrict__ Wr,    // [H,H]
    const float* __restrict__ Ur,    // [H,H]
    const float* __restrict__ Vw,    // [H]
    const float* __restrict__ Vb,    // [1]
    float* __restrict__ out)         // [B,V], zeroed by rrd_fill2x
{
    const int b    = blockIdx.x;
    const int tid  = threadIdx.x;
    const int lane = tid & 63;
    const int wave = tid >> 6;

    __shared__ float s_am[S * H];      // 12.8 KB, linear
    __shared__ float s_Ur[H * 65];     // pad 65: per-lane row reads conflict-free
    __shared__ float s_l[H];
    __shared__ float s_sc[S];

    // ---- stage am: 800 coalesced float4 ----
    {
        const float4* src = reinterpret_cast<const float4*>(am + (size_t)b * S * H);
        float4*       dst = reinterpret_cast<float4*>(s_am);
        #pragma unroll
        for (int i = tid; i < S * H / 4; i += 256) dst[i] = src[i];
    }
    // ---- stage Ur: coalesced float4 -> padded LDS ----
    {
        const float4* src = reinterpret_cast<const float4*>(Ur);
        #pragma unroll
        for (int i = tid; i < H * H / 4; i += 256) {
            float4 u = src[i];
            const int r = (4 * i) >> 6, c = (4 * i) & 63;
            float* d = &s_Ur[r * 65 + c];
            d[0] = u.x; d[1] = u.y; d[2] = u.z; d[3] = u.w;
        }
    }
    // ---- l[k] = <lm[b,:], Wr[k,:]> (one wave; Wr 16 KB, L2-hot) ----
    if (tid < H) {
        const float4* w4 = reinterpret_cast<const float4*>(Wr + tid * H);
        const float4* l4 = reinterpret_cast<const float4*>(lm + (size_t)b * H);
        float acc = 0.f;
        #pragma unroll
        for (int i = 0; i < H / 4; ++i) {
            float4 w = w4[i], x = l4[i];
            acc = fmaf(x.x, w.x, acc); acc = fmaf(x.y, w.y, acc);
            acc = fmaf(x.z, w.z, acc); acc = fmaf(x.w, w.w, acc);
        }
        s_l[tid] = acc;
    }
    const int   my_item = (tid < S) ? items[b * S + tid] : 0;  // prefetch
    const float vb      = Vb[0];
    const float vw      = Vw[lane];
    __syncthreads();   // barrier 1: staging + s_l visible

    // ---- per-lane Ur row from LDS (stride 65 -> conflict-free) ----
    float ur[H];
    #pragma unroll
    for (int h = 0; h < H; ++h) ur[h] = s_Ur[lane * 65 + h];
    const float lk = s_l[lane];

    // ---- scores: wave w handles s = w, w+4, ... (broadcast LDS reads) ----
    for (int s = wave; s < S; s += 4) {
        const float4* a4 = reinterpret_cast<const float4*>(s_am + s * H);
        float acc = lk;
        #pragma unroll
        for (int i = 0; i < H / 4; ++i) {
            float4 v = a4[i];
            acc = fmaf(v.x, ur[4 * i + 0], acc);
            acc = fmaf(v.y, ur[4 * i + 1], acc);
            acc = fmaf(v.z, ur[4 * i + 2], acc);
            acc = fmaf(v.w, ur[4 * i + 3], acc);
        }
        float t = tanhf(acc) * vw;
        #pragma unroll
        for (int off = 32; off; off >>= 1) t += __shfl_xor(t, off, 64);
        if (lane == 0) s_sc[s] = t + vb;
    }
    __syncthreads();   // barrier 2: s_sc visible to wave 0

    // ---- softmax over S=50 + scatter (wave 0, registers only) ----
    if (wave == 0) {
        float x = (lane < S) ? s_sc[lane] : -INFINITY;
        float m = x;
        #pragma unroll
        for (int off = 32; off; off >>= 1) m = fmaxf(m, __shfl_xor(m, off, 64));
        float e = (lane < S) ? expf(x - m) : 0.f;
        float sum = e;
        #pragma unroll
        for (int off = 32; off; off >>= 1) sum += __shfl_xor(sum, off, 64);
        if (lane < S)
            atomicAdd(out + (size_t)b * V + my_item, e / sum);  // dups accumulate
    }
}

extern "C" void kernel_launch(void* const* d_in, const int* in_sizes, int n_in,
                              void* d_out, int out_size, void* d_ws, size_t ws_size,
                              hipStream_t stream) {
    const float* am    = (const float*)d_in[0];  // all_memory [B,S,H]
    const float* lm    = (const float*)d_in[1];  // last_memory [B,H]
    const int*   items = (const int*)  d_in[2];  // seq_item [B,S]
    const float* Wr    = (const float*)d_in[3];  // [H,H]
    const float* Ur    = (const float*)d_in[4];  // [H,H]
    const float* Vw    = (const float*)d_in[5];  // [H]
    const float* Vb    = (const float*)d_in[6];  // scalar
    float* out = (float*)d_out;                  // [B,V] fp32

    // Double-sweep blit-style zero (diagnostic: see kernel comment).
    rrd_fill2x<<<dim3(N4 / 256), dim3(256), 0, stream>>>(
        reinterpret_cast<floatx4*>(out));

    rrd_compute<<<dim3(B), dim3(256), 0, stream>>>(
        am, lm, items, Wr, Ur, Vw, Vb, out);
}

// Round 8
// 189.025 us; speedup vs baseline: 1.1343x; 1.1343x over previous
//
#include <hip/hip_runtime.h>
#include <math.h>

// Problem constants (match reference)
constexpr int B = 1024;
constexpr int S = 50;
constexpr int H = 64;
constexpr int V = 40000;

// ---------------------------------------------------------------------------
// Measured-best structure (R3, 190.6 us total). Single fused dispatch.
// Session accounting (7 rounds): total = poison fill (~98 us, harness) +
// reset/launch overhead (~57 us, harness) + THIS kernel (~33 us).
// Kernel floor is ~28 us: mandatory 164 MB output zero at fill-rate (~25 us)
// overlapped with the ~13 us score loop. Ordering is vmcnt-optimal:
//   staging loads -> barrier 1 (drains loads) -> zero stores issued ->
//   LDS-only score loop (no vmcnt waits!) -> barrier 2 (drains stores) ->
//   softmax + atomics (own row: ordering safe within block).
// ---------------------------------------------------------------------------
__global__ __launch_bounds__(256, 4) void rrd_fused_v3(
    const float* __restrict__ am,    // [B,S,H]
    const float* __restrict__ lm,    // [B,H]
    const int*   __restrict__ items, // [B,S] int32
    const float* __restrict__ Wr,    // [H,H]
    const float* __restrict__ Ur,    // [H,H]
    const float* __restrict__ Vw,    // [H]
    const float* __restrict__ Vb,    // [1]
    float* __restrict__ out)         // [B,V]
{
    const int b    = blockIdx.x;
    const int tid  = threadIdx.x;
    const int lane = tid & 63;
    const int wave = tid >> 6;

    __shared__ float s_am[S * H];      // 12.8 KB, linear
    __shared__ float s_Ur[H * 65];     // pad 65: row reads conflict-free
    __shared__ float s_l[H];
    __shared__ float s_sc[S];

    // ---- stage am: 800 coalesced float4, fully unrolled ----
    {
        const float4* src = reinterpret_cast<const float4*>(am + (size_t)b * S * H);
        float4*       dst = reinterpret_cast<float4*>(s_am);
        #pragma unroll
        for (int i = tid; i < S * H / 4; i += 256) dst[i] = src[i];
    }
    // ---- stage Ur: 1024 coalesced float4 -> padded LDS (4 scalar writes,
    //      2-way bank alias only = free) ----
    {
        const float4* src = reinterpret_cast<const float4*>(Ur);
        #pragma unroll
        for (int i = tid; i < H * H / 4; i += 256) {
            float4 u = src[i];
            const int r = (4 * i) >> 6, c = (4 * i) & 63;
            float* d = &s_Ur[r * 65 + c];
            d[0] = u.x; d[1] = u.y; d[2] = u.z; d[3] = u.w;
        }
    }
    // ---- l[k] = <lm[b,:], Wr[k,:]> (one wave; Wr is 16 KB, L2-hot) ----
    if (tid < H) {
        const float4* w4 = reinterpret_cast<const float4*>(Wr + tid * H);
        const float4* l4 = reinterpret_cast<const float4*>(lm + (size_t)b * H);
        float acc = 0.f;
        #pragma unroll
        for (int i = 0; i < H / 4; ++i) {
            float4 w = w4[i], x = l4[i];
            acc = fmaf(x.x, w.x, acc); acc = fmaf(x.y, w.y, acc);
            acc = fmaf(x.z, w.z, acc); acc = fmaf(x.w, w.w, acc);
        }
        s_l[tid] = acc;
    }
    const int   my_item = (tid < S) ? items[b * S + tid] : 0;  // prefetch
    const float vb      = Vb[0];
    const float vw      = Vw[lane];
    __syncthreads();   // barrier 1: staging + s_l visible (no stores yet)

    // ---- issue row-zero stores now; they drain under the score loop ----
    {
        float4* row4 = reinterpret_cast<float4*>(out + (size_t)b * V);
        const float4 z = make_float4(0.f, 0.f, 0.f, 0.f);
        #pragma unroll 10
        for (int i = tid; i < V / 4; i += 256) row4[i] = z;
    }

    // ---- per-lane Ur row from LDS (stride 65 -> conflict-free) ----
    float ur[H];
    #pragma unroll
    for (int h = 0; h < H; ++h) ur[h] = s_Ur[lane * 65 + h];
    const float lk = s_l[lane];

    // ---- scores: wave w handles s = w, w+4, ... (broadcast LDS reads) ----
    for (int s = wave; s < S; s += 4) {
        const float4* a4 = reinterpret_cast<const float4*>(s_am + s * H);
        float acc = lk;
        #pragma unroll
        for (int i = 0; i < H / 4; ++i) {
            float4 v = a4[i];
            acc = fmaf(v.x, ur[4 * i + 0], acc);
            acc = fmaf(v.y, ur[4 * i + 1], acc);
            acc = fmaf(v.z, ur[4 * i + 2], acc);
            acc = fmaf(v.w, ur[4 * i + 3], acc);
        }
        float t = tanhf(acc) * vw;
        #pragma unroll
        for (int off = 32; off; off >>= 1) t += __shfl_xor(t, off, 64);
        if (lane == 0) s_sc[s] = t + vb;
    }
    __syncthreads();   // barrier 2: s_sc visible; also drains zero stores

    // ---- softmax over S=50 + scatter (wave 0, registers only) ----
    if (wave == 0) {
        float x = (lane < S) ? s_sc[lane] : -INFINITY;
        float m = x;
        #pragma unroll
        for (int off = 32; off; off >>= 1) m = fmaxf(m, __shfl_xor(m, off, 64));
        float e = (lane < S) ? expf(x - m) : 0.f;
        float sum = e;
        #pragma unroll
        for (int off = 32; off; off >>= 1) sum += __shfl_xor(sum, off, 64);
        if (lane < S)
            atomicAdd(out + (size_t)b * V + my_item, e / sum);  // dups accumulate
    }
}

extern "C" void kernel_launch(void* const* d_in, const int* in_sizes, int n_in,
                              void* d_out, int out_size, void* d_ws, size_t ws_size,
                              hipStream_t stream) {
    const float* am    = (const float*)d_in[0];  // all_memory [B,S,H]
    const float* lm    = (const float*)d_in[1];  // last_memory [B,H]
    const int*   items = (const int*)  d_in[2];  // seq_item [B,S]
    const float* Wr    = (const float*)d_in[3];  // [H,H]
    const float* Ur    = (const float*)d_in[4];  // [H,H]
    const float* Vw    = (const float*)d_in[5];  // [H]
    const float* Vb    = (const float*)d_in[6];  // scalar
    float* out = (float*)d_out;                  // [B,V] fp32

    rrd_fused_v3<<<dim3(B), dim3(256), 0, stream>>>(
        am, lm, items, Wr, Ur, Vw, Vb, out);
}